// Round 1
// baseline (522.152 us; speedup 1.0000x reference)
//
#include <hip/hip_runtime.h>

// BlockAxialDown: pool2x2 -> axial attn (H)+(W) -> relu -> concat -> 1x1 conv
// -> relu -> batch-stat BN -> NCHW.  B=8 C=128 H2=W2=128 E=256, heads=2 dh=64.

typedef short v8s __attribute__((ext_vector_type(8)));
typedef short v4s __attribute__((ext_vector_type(4)));
typedef float v4f __attribute__((ext_vector_type(4)));

#define LSA 136   // attn LDS row stride (bf16 elems); 136 -> bank 4*((r+g)%8), balanced
#define LSC 264   // conv LDS row stride

static __device__ __forceinline__ short f2bf(float f){
  unsigned u = __builtin_bit_cast(unsigned, f);
  u = (u + 0x7FFFu + ((u >> 16) & 1u)) >> 16;   // RNE
  return (short)u;
}

// ---------------- prep: transpose weights to bf16 [out][in]; zero stats ----
__global__ void prep_kernel(const float* __restrict__ Wq_h, const float* __restrict__ Wkv_h,
                            const float* __restrict__ Wout_h, const float* __restrict__ Wq_w,
                            const float* __restrict__ Wkv_w, const float* __restrict__ Wout_w,
                            const float* __restrict__ conv_w, short* __restrict__ wt,
                            float* __restrict__ stats){
  int idx = blockIdx.x * 256 + threadIdx.x;   // 768*256 = 196608 exactly
  if (idx < 512) stats[idx] = 0.0f;
  const float* src; int K, O, base;
  if      (idx <  16384){ base = 0;      K=128; O=128; src=Wq_h;  }
  else if (idx <  49152){ base = 16384;  K=128; O=256; src=Wkv_h; }
  else if (idx <  65536){ base = 49152;  K=128; O=128; src=Wout_h;}
  else if (idx <  81920){ base = 65536;  K=128; O=128; src=Wq_w;  }
  else if (idx < 114688){ base = 81920;  K=128; O=256; src=Wkv_w; }
  else if (idx < 131072){ base = 114688; K=128; O=128; src=Wout_w;}
  else                  { base = 131072; K=256; O=256; src=conv_w;}
  int local = idx - base;
  int o = local / K, i = local - o * K;
  wt[idx] = f2bf(src[i * O + o]);   // dst[o][i] = src[i][o]
}

// ---------------- maxpool 2x2 -> channels-last bf16 ----------------------
__global__ void pool_kernel(const float* __restrict__ x, short* __restrict__ xp){
  int bx = blockIdx.x;              // (b*128+i)*2 + jh
  int jh = bx & 1, row = bx >> 1;
  int b = row >> 7, i = row & 127;
  int tid = (int)threadIdx.x;
  int j = jh * 64 + (tid & 63);     // lanes = consecutive j -> coalesced reads
  int cq = tid >> 6;
  for (int rep = 0; rep < 8; ++rep){
    int c0 = (rep * 4 + cq) * 4;
    v4s outv;
    for (int cc = 0; cc < 4; ++cc){
      int c = c0 + cc;
      const float* p0 = x + (((b*128 + c)*256 + 2*i)*256 + 2*j);
      float2 a  = *(const float2*)p0;
      float2 bb = *(const float2*)(p0 + 256);
      outv[cc] = f2bf(fmaxf(fmaxf(a.x, a.y), fmaxf(bb.x, bb.y)));
    }
    *(v4s*)(xp + ((row*128 + j)*128 + c0)) = outv;   // 8B per lane
  }
}

// ---------------- fused axial attention, one (b,s) per block --------------
// DIR=0: H-attn (s=w, t=h, weights _h).  DIR=1: W-attn (s=h, t=w, weights _w, acc +=).
template<int DIR>
__global__ __launch_bounds__(512, 2)
void attn_kernel(const short* __restrict__ xp, const short* __restrict__ wt,
                 const float* __restrict__ bout, float* __restrict__ acc){
  __shared__ short xs[128*LSA];   // x tile; reused as P
  __shared__ short qs[128*LSA];   // q;     reused as O
  __shared__ short ks[128*LSA];
  __shared__ short vs[128*LSA];   // v transposed: [channel][t]

  const int bx = blockIdx.x;
  const int b = bx >> 7, s = bx & 127;
  const int tid = (int)threadIdx.x;
  const int wv = tid >> 6;
  const int lane = tid & 63;
  const int l15 = lane & 15, l4 = lane >> 4;

  const short* WqT   = wt + (DIR == 0 ? 0     : 65536);
  const short* WkvT  = wt + (DIR == 0 ? 16384 : 81920);
  const short* WoutT = wt + (DIR == 0 ? 49152 : 114688);

  // ---- stage x tile [t][c] ----
  for (int r = 0; r < 4; ++r){
    int idx = (r*512 + tid) * 8;
    int t = idx >> 7, c = idx & 127;
    int gi = (DIR == 0) ? (((b*128 + t)*128 + s)*128 + c)
                        : (((b*128 + s)*128 + t)*128 + c);
    *(v8s*)(&xs[t*LSA + c]) = *(const v8s*)(xp + gi);
  }
  __syncthreads();

  // ---- Phase A: q,k,v = x @ {Wq, Wkv}  (wave = 16-row t band) ----
  v8s av[4];
  for (int kk = 0; kk < 4; ++kk)
    av[kk] = *(const v8s*)(&xs[(16*wv + l15)*LSA + kk*32 + l4*8]);

  for (int m = 0; m < 3; ++m){
    const short* W = (m == 0) ? WqT : (WkvT + (m == 2 ? 16384 : 0));
    for (int tc = 0; tc < 8; ++tc){
      v4f d = {0.f, 0.f, 0.f, 0.f};
      for (int kk = 0; kk < 4; ++kk){
        v8s bf = *(const v8s*)(W + (tc*16 + l15)*128 + kk*32 + l4*8);
        d = __builtin_amdgcn_mfma_f32_16x16x32_bf16(av[kk], bf, d, 0, 0, 0);
      }
      if (m == 2){                       // v stored transposed: vs[n][t], 8B contig
        v4s pk;
        for (int r = 0; r < 4; ++r) pk[r] = f2bf(d[r]);
        *(v4s*)(&vs[(16*tc + l15)*LSA + 16*wv + 4*l4]) = pk;
      } else {
        short* dst = (m == 0) ? qs : ks; // [t][c]
        for (int r = 0; r < 4; ++r)
          dst[(16*wv + 4*l4 + r)*LSA + 16*tc + l15] = f2bf(d[r]);
      }
    }
  }
  __syncthreads();

  // ---- Phase B: per head, S^T = K·Q^T, softmax over j, O = P·V ----
  for (int h = 0; h < 2; ++h){
    v8s bq[2];
    for (int kk = 0; kk < 2; ++kk)
      bq[kk] = *(const v8s*)(&qs[(16*wv + l15)*LSA + h*64 + kk*32 + l4*8]);
    v4f st[8];                           // S^T[j = 16jt+4l4+r][i = 16wv+l15]
    for (int jt = 0; jt < 8; ++jt){
      v4f d = {0.f, 0.f, 0.f, 0.f};
      for (int kk = 0; kk < 2; ++kk){
        v8s ak = *(const v8s*)(&ks[(16*jt + l15)*LSA + h*64 + kk*32 + l4*8]);
        d = __builtin_amdgcn_mfma_f32_16x16x32_bf16(ak, bq[kk], d, 0, 0, 0);
      }
      st[jt] = d;
    }
    // softmax over j for this lane's column i (32 local + 2 shuffles over l4 groups)
    float mx = -1e30f;
    for (int jt = 0; jt < 8; ++jt)
      for (int r = 0; r < 4; ++r) mx = fmaxf(mx, st[jt][r]);
    mx = fmaxf(mx, __shfl_xor(mx, 16));
    mx = fmaxf(mx, __shfl_xor(mx, 32));
    float sm = 0.f;
    for (int jt = 0; jt < 8; ++jt)
      for (int r = 0; r < 4; ++r){
        float e = __expf((st[jt][r] - mx) * 0.125f);   // * dh^-0.5
        st[jt][r] = e; sm += e;
      }
    sm += __shfl_xor(sm, 16);
    sm += __shfl_xor(sm, 32);
    float inv = 1.0f / sm;
    for (int jt = 0; jt < 8; ++jt){      // P -> LDS (xs), row i, 8B contig
      v4s pk;
      for (int r = 0; r < 4; ++r) pk[r] = f2bf(st[jt][r] * inv);
      *(v4s*)(&xs[(16*wv + l15)*LSA + 16*jt + 4*l4]) = pk;
    }
    v8s pa[4];
    for (int kk = 0; kk < 4; ++kk)
      pa[kk] = *(const v8s*)(&xs[(16*wv + l15)*LSA + kk*32 + l4*8]);
    for (int tc = 0; tc < 4; ++tc){      // O-band [i][d], B from vs^T
      v4f d = {0.f, 0.f, 0.f, 0.f};
      for (int kk = 0; kk < 4; ++kk){
        v8s vb = *(const v8s*)(&vs[(h*64 + 16*tc + l15)*LSA + kk*32 + l4*8]);
        d = __builtin_amdgcn_mfma_f32_16x16x32_bf16(pa[kk], vb, d, 0, 0, 0);
      }
      for (int r = 0; r < 4; ++r)        // O -> qs (head-h q cols are dead now)
        qs[(16*wv + 4*l4 + r)*LSA + h*64 + 16*tc + l15] = f2bf(d[r]);
    }
  }
  __syncthreads();

  // ---- Phase C: Z^T = WoutT · O^T + bias; store (float4 along channels) ----
  v8s aw[4];
  for (int kk = 0; kk < 4; ++kk)
    aw[kk] = *(const v8s*)(WoutT + (16*wv + l15)*128 + kk*32 + l4*8);
  float bb[4];
  for (int r = 0; r < 4; ++r) bb[r] = bout[16*wv + 4*l4 + r];
  for (int tc = 0; tc < 8; ++tc){
    v4f d = {0.f, 0.f, 0.f, 0.f};
    for (int kk = 0; kk < 4; ++kk){
      v8s ob = *(const v8s*)(&qs[(16*tc + l15)*LSA + kk*32 + l4*8]);
      d = __builtin_amdgcn_mfma_f32_16x16x32_bf16(aw[kk], ob, d, 0, 0, 0);
    }
    int i  = 16*tc + l15;        // token position along the attended axis
    int jc = 16*wv + 4*l4;       // first of 4 output channels
    int o = (DIR == 0) ? (((b*128 + i)*128 + s)*128 + jc)
                       : (((b*128 + s)*128 + i)*128 + jc);
    v4f z;
    for (int r = 0; r < 4; ++r) z[r] = d[r] + bb[r];
    if (DIR == 0){
      *(v4f*)(acc + o) = z;
    } else {
      v4f old = *(const v4f*)(acc + o);
      for (int r = 0; r < 4; ++r) z[r] += old[r];
      *(v4f*)(acc + o) = z;
    }
  }
}

// ---------------- concat + 1x1 conv + relu + BN partial stats -------------
__global__ __launch_bounds__(512, 2)
void conv_kernel(const float* __restrict__ aacc, const short* __restrict__ xp,
                 const short* __restrict__ wt, float* __restrict__ out,
                 float* __restrict__ stats){
  __shared__ short cat[128*LSC];
  __shared__ float lsum[256];
  __shared__ float lsq[256];
  const short* convT = wt + 131072;    // [e][f] bf16
  int bx = blockIdx.x;                 // b*128 + i (one image row = 128 tokens)
  int b = bx >> 7, ii = bx & 127;
  int tid = (int)threadIdx.x;
  int wv = tid >> 6, lane = tid & 63, l15 = lane & 15, l4 = lane >> 4;
  if (tid < 256){ lsum[tid] = 0.f; lsq[tid] = 0.f; }
  // f in [0,128): relu(a_h + a_w)
  for (int r = 0; r < 8; ++r){
    int idx = (r*512 + tid) * 4;
    int t = idx >> 7, c = idx & 127;
    v4f v = *(const v4f*)(aacc + ((bx*128 + t)*128 + c));
    v4s pk;
    for (int k = 0; k < 4; ++k) pk[k] = f2bf(fmaxf(v[k], 0.f));
    *(v4s*)(&cat[t*LSC + c]) = pk;
  }
  // f in [128,256): pooled x
  for (int r = 0; r < 4; ++r){
    int idx = (r*512 + tid) * 8;
    int t = idx >> 7, c = idx & 127;
    *(v8s*)(&cat[t*LSC + 128 + c]) = *(const v8s*)(xp + ((bx*128 + t)*128 + c));
  }
  __syncthreads();
  v8s af[8];
  for (int kk = 0; kk < 8; ++kk)
    af[kk] = *(const v8s*)(&cat[(16*wv + l15)*LSC + kk*32 + l4*8]);
  for (int tc = 0; tc < 16; ++tc){
    v4f d = {0.f, 0.f, 0.f, 0.f};
    for (int kk = 0; kk < 8; ++kk){
      v8s bf = *(const v8s*)(convT + (tc*16 + l15)*256 + kk*32 + l4*8);
      d = __builtin_amdgcn_mfma_f32_16x16x32_bf16(af[kk], bf, d, 0, 0, 0);
    }
    int e  = 16*tc + l15;
    int j0 = 16*wv + 4*l4;
    v4f y;
    float s1 = 0.f, s2 = 0.f;
    for (int r = 0; r < 4; ++r){
      y[r] = fmaxf(d[r], 0.f);
      s1 += y[r]; s2 += y[r]*y[r];
    }
    *(v4f*)(out + (((b*256 + e)*128 + ii)*128 + j0)) = y;   // pre-BN y, NCHW
    s1 += __shfl_xor(s1, 16); s1 += __shfl_xor(s1, 32);
    s2 += __shfl_xor(s2, 16); s2 += __shfl_xor(s2, 32);
    if (l4 == 0){
      atomicAdd(&lsum[e], s1);
      atomicAdd(&lsq[e], s2);
    }
  }
  __syncthreads();
  if (tid < 256){
    atomicAdd(&stats[tid],       lsum[tid]);
    atomicAdd(&stats[256 + tid], lsq[tid]);
  }
}

// ---------------- BN normalize in place -----------------------------------
__global__ void bn_kernel(float* __restrict__ out, const float* __restrict__ stats,
                          const float* __restrict__ gamma, const float* __restrict__ beta){
  const float invn = 1.0f / 131072.0f;
  long stride = (long)gridDim.x * blockDim.x * 4;
  for (long idx = ((long)blockIdx.x * blockDim.x + threadIdx.x) * 4;
       idx < 33554432L; idx += stride){
    int e = (int)((idx >> 14) & 255);
    float m  = stats[e] * invn;
    float var = stats[256 + e] * invn - m * m;
    float sc = gamma[e] * rsqrtf(var + 1e-5f);
    float sh = beta[e] - m * sc;
    v4f v = *(v4f*)(out + idx);
    for (int r = 0; r < 4; ++r) v[r] = v[r]*sc + sh;
    *(v4f*)(out + idx) = v;
  }
}

extern "C" void kernel_launch(void* const* d_in, const int* in_sizes, int n_in,
                              void* d_out, int out_size, void* d_ws, size_t ws_size,
                              hipStream_t stream){
  const float* x      = (const float*)d_in[0];
  const float* Wq_h   = (const float*)d_in[1];
  const float* Wkv_h  = (const float*)d_in[2];
  const float* Wout_h = (const float*)d_in[3];
  const float* bout_h = (const float*)d_in[4];
  const float* Wq_w   = (const float*)d_in[5];
  const float* Wkv_w  = (const float*)d_in[6];
  const float* Wout_w = (const float*)d_in[7];
  const float* bout_w = (const float*)d_in[8];
  const float* conv_w = (const float*)d_in[9];
  const float* gamma  = (const float*)d_in[10];
  const float* beta   = (const float*)d_in[11];
  float* out = (float*)d_out;

  char* ws = (char*)d_ws;
  short* xp    = (short*)(ws);               // 33,554,432 B  bf16 pooled NHWC
  float* aacc  = (float*)(ws + 33554432);    // 67,108,864 B  attn sum fp32
  short* wt    = (short*)(ws + 100663296);   //    393,216 B  bf16 W^T pack
  float* stats = (float*)(ws + 101056512);   //      2,048 B  BN sums

  prep_kernel<<<768, 256, 0, stream>>>(Wq_h, Wkv_h, Wout_h, Wq_w, Wkv_w, Wout_w,
                                       conv_w, wt, stats);
  pool_kernel<<<2048, 256, 0, stream>>>(x, xp);
  attn_kernel<0><<<1024, 512, 0, stream>>>(xp, wt, bout_h, aacc);
  attn_kernel<1><<<1024, 512, 0, stream>>>(xp, wt, bout_w, aacc);
  conv_kernel<<<1024, 512, 0, stream>>>(aacc, xp, wt, out, stats);
  bn_kernel<<<2048, 256, 0, stream>>>(out, stats, gamma, beta);
}

// Round 2
// 516.547 us; speedup vs baseline: 1.0108x; 1.0108x over previous
//
#include <hip/hip_runtime.h>

// BlockAxialDown: pool2x2 -> axial attn (H)+(W) -> relu -> concat -> 1x1 conv
// -> relu -> batch-stat BN -> NCHW.  B=8 C=128 H2=W2=128 E=256, heads=2 dh=64.
//
// Dataflow (all bf16 activations in ws):
//   pool  -> cat[tok][128:256]  (tok = (b,h,w), pooled x, bf16)
//   attn0 -> ah[tok][0:128]     (a_h, bf16)
//   attn1 -> cat[tok][0:128]    (relu(a_h + a_w), bf16)
//   conv  -> d_out fp32 NCHW (pre-BN) + 16-way-spread channel stats
//   bn    -> RMW d_out with per-channel scale/shift

typedef short v8s __attribute__((ext_vector_type(8)));
typedef short v4s __attribute__((ext_vector_type(4)));
typedef float v4f __attribute__((ext_vector_type(4)));

#define LSA 136   // attn LDS row stride; 272B -> bank offset 4/row, 2-way (free)
#define LSC 264   // conv LDS row stride; 528B -> bank offset 4/row, 2-way (free)

static __device__ __forceinline__ short f2bf(float f){
  unsigned u = __builtin_bit_cast(unsigned, f);
  u = (u + 0x7FFFu + ((u >> 16) & 1u)) >> 16;   // RNE
  return (short)u;
}
static __device__ __forceinline__ float bf2f(short s){
  unsigned u = ((unsigned)(unsigned short)s) << 16;
  return __builtin_bit_cast(float, u);
}

// ---------------- prep: transpose weights to bf16 [out][in]; zero stats ----
__global__ void prep_kernel(const float* __restrict__ Wq_h, const float* __restrict__ Wkv_h,
                            const float* __restrict__ Wout_h, const float* __restrict__ Wq_w,
                            const float* __restrict__ Wkv_w, const float* __restrict__ Wout_w,
                            const float* __restrict__ conv_w, short* __restrict__ wt,
                            float* __restrict__ stats){
  int idx = blockIdx.x * 256 + threadIdx.x;   // 768*256 = 196608 exactly
  if (idx < 8192) stats[idx] = 0.0f;          // 16 copies x 512
  const float* src; int K, O, base;
  if      (idx <  16384){ base = 0;      K=128; O=128; src=Wq_h;  }
  else if (idx <  49152){ base = 16384;  K=128; O=256; src=Wkv_h; }
  else if (idx <  65536){ base = 49152;  K=128; O=128; src=Wout_h;}
  else if (idx <  81920){ base = 65536;  K=128; O=128; src=Wq_w;  }
  else if (idx < 114688){ base = 81920;  K=128; O=256; src=Wkv_w; }
  else if (idx < 131072){ base = 114688; K=128; O=128; src=Wout_w;}
  else                  { base = 131072; K=256; O=256; src=conv_w;}
  int local = idx - base;
  int o = local / K, i = local - o * K;
  wt[idx] = f2bf(src[i * O + o]);   // dst[o][i] = src[i][o]
}

// ---------------- maxpool 2x2 -> bf16 into cat[tok][128:256] --------------
__global__ void pool_kernel(const float* __restrict__ x, short* __restrict__ cat){
  int bx = blockIdx.x;              // (b*128+i)*2 + jh
  int jh = bx & 1, row = bx >> 1;
  int b = row >> 7, i = row & 127;
  int tid = (int)threadIdx.x;
  int j = jh * 64 + (tid & 63);     // lanes = consecutive j -> coalesced reads
  int cq = tid >> 6;
  for (int rep = 0; rep < 8; ++rep){
    int c0 = (rep * 4 + cq) * 4;
    v4s outv;
    for (int cc = 0; cc < 4; ++cc){
      int c = c0 + cc;
      const float* p0 = x + (((b*128 + c)*256 + 2*i)*256 + 2*j);
      float2 a  = *(const float2*)p0;
      float2 bb = *(const float2*)(p0 + 256);
      outv[cc] = f2bf(fmaxf(fmaxf(a.x, a.y), fmaxf(bb.x, bb.y)));
    }
    *(v4s*)(cat + ((row*128 + j)*256 + 128 + c0)) = outv;   // 8B per lane
  }
}

// ---------------- fused axial attention, one (b,s) per 1024-thr block -----
// 16 waves: wave = (band w = wv>>1, half/head p = wv&1).
// DIR=0: H-attn (s=w-coord, t=h-coord, weights _h) -> ah bf16.
// DIR=1: W-attn (s=h-coord, t=w-coord, weights _w) -> cat[:,0:128] = relu(ah + a_w).
template<int DIR>
__global__ __launch_bounds__(1024, 4)
void attn_kernel(short* __restrict__ cat, const short* __restrict__ wt,
                 const float* __restrict__ bout, short* __restrict__ ah){
  __shared__ short buf0[128*LSA];   // x -> q -> P(h0) -> O
  __shared__ short ks[128*LSA];     // k -> P(h1)
  __shared__ short vs[128*LSA];     // v transposed: [channel][t]

  const int bx = blockIdx.x;
  const int b = bx >> 7, s = bx & 127;
  const int tid = (int)threadIdx.x;
  const int wv = tid >> 6;
  const int w = wv >> 1;            // 16-row band 0..7
  const int p = wv & 1;             // tc-half in A/C, head in B
  const int lane = tid & 63;
  const int l15 = lane & 15, l4 = lane >> 4;

  const short* WqT   = wt + (DIR == 0 ? 0     : 65536);
  const short* WkvT  = wt + (DIR == 0 ? 16384 : 81920);
  const short* WoutT = wt + (DIR == 0 ? 49152 : 114688);

  // ---- stage x tile [t][c] from cat second half ----
  for (int r = 0; r < 2; ++r){
    int idx = (r*1024 + tid) * 8;
    int t = idx >> 7, c = idx & 127;
    int tok = (DIR == 0) ? ((b*128 + t)*128 + s) : ((b*128 + s)*128 + t);
    *(v8s*)(&buf0[t*LSA + c]) = *(const v8s*)(cat + tok*256 + 128 + c);
  }
  __syncthreads();

  // all waves snapshot their band's x into regs before q overwrites buf0
  v8s av[4];
  for (int kk = 0; kk < 4; ++kk)
    av[kk] = *(const v8s*)(&buf0[(16*w + l15)*LSA + kk*32 + l4*8]);
  __syncthreads();

  // ---- Phase A: q,k,v = x @ {Wq, Wkv}; wave pair splits out-col halves ----
  for (int m = 0; m < 3; ++m){
    const short* W = (m == 0) ? WqT : (WkvT + (m == 2 ? 16384 : 0));
    for (int tcl = 0; tcl < 4; ++tcl){
      int tc = p*4 + tcl;
      v4f d = {0.f, 0.f, 0.f, 0.f};
      for (int kk = 0; kk < 4; ++kk){
        v8s bf = *(const v8s*)(W + (tc*16 + l15)*128 + kk*32 + l4*8);
        d = __builtin_amdgcn_mfma_f32_16x16x32_bf16(av[kk], bf, d, 0, 0, 0);
      }
      if (m == 2){                       // v transposed: vs[n][t], 8B contig
        v4s pk;
        for (int r = 0; r < 4; ++r) pk[r] = f2bf(d[r]);
        *(v4s*)(&vs[(16*tc + l15)*LSA + 16*w + 4*l4]) = pk;
      } else {
        short* dst = (m == 0) ? buf0 : ks;   // [t][c]
        for (int r = 0; r < 4; ++r)
          dst[(16*w + 4*l4 + r)*LSA + 16*tc + l15] = f2bf(d[r]);
      }
    }
  }
  __syncthreads();

  // ---- Phase B: wave handles head h=p for its band: S^T=K.Q^T, softmax, PV -
  const int h = p;
  v8s bq[2];
  for (int kk = 0; kk < 2; ++kk)
    bq[kk] = *(const v8s*)(&buf0[(16*w + l15)*LSA + h*64 + kk*32 + l4*8]);
  v4f st[8];                           // S^T[j = 16jt+4l4+r][i = 16w+l15]
  for (int jt = 0; jt < 8; ++jt){
    v4f d = {0.f, 0.f, 0.f, 0.f};
    for (int kk = 0; kk < 2; ++kk){
      v8s ak = *(const v8s*)(&ks[(16*jt + l15)*LSA + h*64 + kk*32 + l4*8]);
      d = __builtin_amdgcn_mfma_f32_16x16x32_bf16(ak, bq[kk], d, 0, 0, 0);
    }
    st[jt] = d;
  }
  float mx = -1e30f;
  for (int jt = 0; jt < 8; ++jt)
    for (int r = 0; r < 4; ++r) mx = fmaxf(mx, st[jt][r]);
  mx = fmaxf(mx, __shfl_xor(mx, 16));
  mx = fmaxf(mx, __shfl_xor(mx, 32));
  float sm = 0.f;
  for (int jt = 0; jt < 8; ++jt)
    for (int r = 0; r < 4; ++r){
      float e = __expf((st[jt][r] - mx) * 0.125f);   // * dh^-0.5
      st[jt][r] = e; sm += e;
    }
  sm += __shfl_xor(sm, 16);
  sm += __shfl_xor(sm, 32);
  float inv = 1.0f / sm;
  __syncthreads();                     // all q/k reads done; P may overwrite

  short* pb = (h == 0) ? buf0 : ks;    // P -> own band rows of buf0 / ks
  for (int jt = 0; jt < 8; ++jt){
    v4s pk;
    for (int r = 0; r < 4; ++r) pk[r] = f2bf(st[jt][r] * inv);
    *(v4s*)(&pb[(16*w + l15)*LSA + 16*jt + 4*l4]) = pk;
  }
  __syncthreads();

  v8s pa[4];
  for (int kk = 0; kk < 4; ++kk)
    pa[kk] = *(const v8s*)(&pb[(16*w + l15)*LSA + kk*32 + l4*8]);
  __syncthreads();                     // pa snapshot before O overwrites buf0

  for (int tc = 0; tc < 4; ++tc){      // O-band [i][d]
    v4f d = {0.f, 0.f, 0.f, 0.f};
    for (int kk = 0; kk < 4; ++kk){
      v8s vb = *(const v8s*)(&vs[(h*64 + 16*tc + l15)*LSA + kk*32 + l4*8]);
      d = __builtin_amdgcn_mfma_f32_16x16x32_bf16(pa[kk], vb, d, 0, 0, 0);
    }
    for (int r = 0; r < 4; ++r)
      buf0[(16*w + 4*l4 + r)*LSA + h*64 + 16*tc + l15] = f2bf(d[r]);
  }
  __syncthreads();

  // ---- Phase C: Z^T = WoutT . O^T + bias; wave pair splits token tiles ----
  v8s aw[4];
  for (int kk = 0; kk < 4; ++kk)
    aw[kk] = *(const v8s*)(WoutT + (16*w + l15)*128 + kk*32 + l4*8);
  float bb[4];
  for (int r = 0; r < 4; ++r) bb[r] = bout[16*w + 4*l4 + r];
  for (int tcl = 0; tcl < 4; ++tcl){
    int tc = p*4 + tcl;
    v4f d = {0.f, 0.f, 0.f, 0.f};
    for (int kk = 0; kk < 4; ++kk){
      v8s ob = *(const v8s*)(&buf0[(16*tc + l15)*LSA + kk*32 + l4*8]);
      d = __builtin_amdgcn_mfma_f32_16x16x32_bf16(aw[kk], ob, d, 0, 0, 0);
    }
    int i  = 16*tc + l15;        // token position along the attended axis
    int jc = 16*w + 4*l4;        // first of 4 output channels
    if (DIR == 0){
      v4s z;
      for (int r = 0; r < 4; ++r) z[r] = f2bf(d[r] + bb[r]);
      *(v4s*)(ah + (((b*128 + i)*128 + s)*128 + jc)) = z;
    } else {
      int tok = (b*128 + s)*128 + i;
      v4s hv = *(const v4s*)(ah + tok*128 + jc);
      v4s z;
      for (int r = 0; r < 4; ++r)
        z[r] = f2bf(fmaxf(d[r] + bb[r] + bf2f(hv[r]), 0.f));
      *(v4s*)(cat + tok*256 + jc) = z;
    }
  }
}

// ---------------- 1x1 conv (M=131072,N=256,K=256) + relu + stats ----------
__global__ __launch_bounds__(512, 2)
void conv_kernel(const short* __restrict__ cat, const short* __restrict__ wt,
                 float* __restrict__ out, float* __restrict__ stats){
  __shared__ short cats[128*LSC];
  __shared__ float lsum[256];
  __shared__ float lsq[256];
  const short* convT = wt + 131072;    // [e][f] bf16
  int bx = blockIdx.x;                 // b*128 + i (one image row = 128 tokens)
  int b = bx >> 7, ii = bx & 127;
  int tid = (int)threadIdx.x;
  int wv = tid >> 6, lane = tid & 63, l15 = lane & 15, l4 = lane >> 4;
  if (tid < 256){ lsum[tid] = 0.f; lsq[tid] = 0.f; }
  for (int r = 0; r < 8; ++r){         // stage [128][256] bf16, coalesced
    int idx = (r*512 + tid) * 8;
    int t = idx >> 8, f = idx & 255;
    *(v8s*)(&cats[t*LSC + f]) = *(const v8s*)(cat + (bx*128 + t)*256 + f);
  }
  __syncthreads();
  v8s af[8];
  for (int kk = 0; kk < 8; ++kk)
    af[kk] = *(const v8s*)(&cats[(16*wv + l15)*LSC + kk*32 + l4*8]);
  for (int tci = 0; tci < 16; ++tci){
    int tc = (tci + wv*2) & 15;        // stagger e-planes across waves
    v4f d = {0.f, 0.f, 0.f, 0.f};
    for (int kk = 0; kk < 8; ++kk){
      v8s bf = *(const v8s*)(convT + (tc*16 + l15)*256 + kk*32 + l4*8);
      d = __builtin_amdgcn_mfma_f32_16x16x32_bf16(af[kk], bf, d, 0, 0, 0);
    }
    int e  = 16*tc + l15;
    int j0 = 16*wv + 4*l4;
    v4f y;
    float s1 = 0.f, s2 = 0.f;
    for (int r = 0; r < 4; ++r){
      y[r] = fmaxf(d[r], 0.f);
      s1 += y[r]; s2 += y[r]*y[r];
    }
    *(v4f*)(out + (((b*256 + e)*128 + ii)*128 + j0)) = y;   // pre-BN y, NCHW
    s1 += __shfl_xor(s1, 16); s1 += __shfl_xor(s1, 32);
    s2 += __shfl_xor(s2, 16); s2 += __shfl_xor(s2, 32);
    if (l4 == 0){
      atomicAdd(&lsum[e], s1);
      atomicAdd(&lsq[e], s2);
    }
  }
  __syncthreads();
  if (tid < 256){
    int c = bx & 15;                   // 16-way spread: 64 blocks/address
    atomicAdd(&stats[c*512 + tid],       lsum[tid]);
    atomicAdd(&stats[c*512 + 256 + tid], lsq[tid]);
  }
}

// ---------------- BN normalize in place (block = one (b,e) plane) ---------
__global__ void bn_kernel(float* __restrict__ out, const float* __restrict__ stats,
                          const float* __restrict__ gamma, const float* __restrict__ beta){
  const float invn = 1.0f / 131072.0f;
  int bx = blockIdx.x;                 // b*256 + e
  int e = bx & 255;
  float s1 = 0.f, s2 = 0.f;
  for (int c = 0; c < 16; ++c){
    s1 += stats[c*512 + e];
    s2 += stats[c*512 + 256 + e];
  }
  float m  = s1 * invn;
  float var = s2 * invn - m * m;
  float sc = gamma[e] * rsqrtf(var + 1e-5f);
  float sh = beta[e] - m * sc;
  long base = (long)bx * 16384;
  int tid = (int)threadIdx.x;
  for (int rep = 0; rep < 16; ++rep){
    long idx = base + rep*1024 + tid*4;
    v4f v = *(v4f*)(out + idx);
    for (int r = 0; r < 4; ++r) v[r] = v[r]*sc + sh;
    *(v4f*)(out + idx) = v;
  }
}

extern "C" void kernel_launch(void* const* d_in, const int* in_sizes, int n_in,
                              void* d_out, int out_size, void* d_ws, size_t ws_size,
                              hipStream_t stream){
  const float* x      = (const float*)d_in[0];
  const float* Wq_h   = (const float*)d_in[1];
  const float* Wkv_h  = (const float*)d_in[2];
  const float* Wout_h = (const float*)d_in[3];
  const float* bout_h = (const float*)d_in[4];
  const float* Wq_w   = (const float*)d_in[5];
  const float* Wkv_w  = (const float*)d_in[6];
  const float* Wout_w = (const float*)d_in[7];
  const float* bout_w = (const float*)d_in[8];
  const float* conv_w = (const float*)d_in[9];
  const float* gamma  = (const float*)d_in[10];
  const float* beta   = (const float*)d_in[11];
  float* out = (float*)d_out;

  char* ws = (char*)d_ws;
  short* cat   = (short*)(ws);               // 67,108,864 B  bf16 [tok][256]
  short* ah    = (short*)(ws + 67108864);    // 33,554,432 B  bf16 [tok][128]
  short* wt    = (short*)(ws + 100663296);   //    393,216 B  bf16 W^T pack
  float* stats = (float*)(ws + 101056512);   //     32,768 B  BN sums x16

  prep_kernel<<<768, 256, 0, stream>>>(Wq_h, Wkv_h, Wout_h, Wq_w, Wkv_w, Wout_w,
                                       conv_w, wt, stats);
  pool_kernel<<<2048, 256, 0, stream>>>(x, cat);
  attn_kernel<0><<<1024, 1024, 0, stream>>>(cat, wt, bout_h, ah);
  attn_kernel<1><<<1024, 1024, 0, stream>>>(cat, wt, bout_w, ah);
  conv_kernel<<<1024, 512, 0, stream>>>(cat, wt, out, stats);
  bn_kernel<<<2048, 256, 0, stream>>>(out, stats, gamma, beta);
}